// Round 1
// baseline (635.151 us; speedup 1.0000x reference)
//
#include <hip/hip_runtime.h>
#include <hip/hip_bf16.h>
#include <math.h>

// Problem constants (from reference setup_inputs: B=16, L=256, D=256, K=16384)
#define NROWS 4096              // B*L anchors / z rows
#define NCAND 20480             // NROWS + K candidates
#define DIM   256               // feature dim
#define TM    128               // anchor rows per block
#define TN    128               // candidate cols per tile
#define BK    32                // k-depth per LDS stage
#define NSLICE 16               // candidate column slices (grid.y)
#define COLS_PER_SLICE (NCAND / NSLICE)      // 1280
#define TILES_PER_SLICE (COLS_PER_SLICE / TN) // 10
#define INV_T (1.0f / 0.07f)

// Kernel A: per 128-row block x per column slice, compute online-softmax
// partials (running max m, running sum-exp s) over that slice's 1280 logits.
// Diagonal (self-sim) elements are skipped. 8x8 register micro-tile per
// thread (16x16 thread grid), LDS-staged A/B tiles in [BK][TM] k-major
// layout so compute reads are float4 with <=2-way bank aliasing (free).
__global__ __launch_bounds__(256) void lse_partial_kernel(
    const float* __restrict__ z, const float* __restrict__ mem,
    float* __restrict__ part_m, float* __restrict__ part_s)
{
    __shared__ float As[BK][TM];
    __shared__ float Bs[BK][TN];
    __shared__ float sm[TM][16];
    __shared__ float ss[TM][16];

    const int tid = threadIdx.x;
    const int tx = tid & 15;   // column group
    const int ty = tid >> 4;   // row group
    const int rowBase = blockIdx.x * TM;
    const int slice = blockIdx.y;

    float mrun[2][4];
    float srun[2][4];
#pragma unroll
    for (int h = 0; h < 2; ++h)
#pragma unroll
        for (int i = 0; i < 4; ++i) { mrun[h][i] = -INFINITY; srun[h][i] = 0.0f; }

    for (int t = 0; t < TILES_PER_SLICE; ++t) {
        const int colBase = slice * COLS_PER_SLICE + t * TN;
        float acc[2][4][2][4];
#pragma unroll
        for (int ah = 0; ah < 2; ++ah)
#pragma unroll
        for (int i = 0; i < 4; ++i)
#pragma unroll
        for (int bh = 0; bh < 2; ++bh)
#pragma unroll
        for (int j = 0; j < 4; ++j)
            acc[ah][i][bh][j] = 0.0f;

        for (int kk = 0; kk < DIM; kk += BK) {
            __syncthreads();   // protect previous stage's LDS reads
            // Stage A tile: 128 rows x 32 k, stored k-major As[k][row].
            // 1024 float4 loads split over 256 threads (4 each).
#pragma unroll
            for (int u = 0; u < 4; ++u) {
                const int f = tid + u * 256;   // 0..1023
                const int r = f >> 3;          // 0..127 row
                const int c4 = f & 7;          // float4 index within 32-k row
                const float4 v = *(const float4*)(z + (size_t)(rowBase + r) * DIM + kk + c4 * 4);
                As[c4 * 4 + 0][r] = v.x;
                As[c4 * 4 + 1][r] = v.y;
                As[c4 * 4 + 2][r] = v.z;
                As[c4 * 4 + 3][r] = v.w;
            }
            // Stage B tile: candidate rows (z for c<4096, memory_queue after)
#pragma unroll
            for (int u = 0; u < 4; ++u) {
                const int f = tid + u * 256;
                const int r = f >> 3;
                const int c4 = f & 7;
                const int c = colBase + r;
                const float* src = (c < NROWS) ? (z + (size_t)c * DIM)
                                               : (mem + (size_t)(c - NROWS) * DIM);
                const float4 v = *(const float4*)(src + kk + c4 * 4);
                Bs[c4 * 4 + 0][r] = v.x;
                Bs[c4 * 4 + 1][r] = v.y;
                Bs[c4 * 4 + 2][r] = v.z;
                Bs[c4 * 4 + 3][r] = v.w;
            }
            __syncthreads();
            // 8x8 micro-tile: rows {ty*4+i, +64}, cols {tx*4+j, +64}
#pragma unroll
            for (int k = 0; k < BK; ++k) {
                float a[2][4], b[2][4];
#pragma unroll
                for (int h = 0; h < 2; ++h) {
                    const float4 av = *(const float4*)&As[k][ty * 4 + h * 64];
                    a[h][0] = av.x; a[h][1] = av.y; a[h][2] = av.z; a[h][3] = av.w;
                    const float4 bv = *(const float4*)&Bs[k][tx * 4 + h * 64];
                    b[h][0] = bv.x; b[h][1] = bv.y; b[h][2] = bv.z; b[h][3] = bv.w;
                }
#pragma unroll
                for (int ah = 0; ah < 2; ++ah)
#pragma unroll
                for (int i = 0; i < 4; ++i)
#pragma unroll
                for (int bh = 0; bh < 2; ++bh)
#pragma unroll
                for (int j = 0; j < 4; ++j)
                    acc[ah][i][bh][j] = fmaf(a[ah][i], b[bh][j], acc[ah][i][bh][j]);
            }
        }

        // Online (m, s) update over this tile's 8x8 logits; skip diagonal.
#pragma unroll
        for (int ah = 0; ah < 2; ++ah)
#pragma unroll
        for (int i = 0; i < 4; ++i) {
            const int grow = rowBase + ty * 4 + i + ah * 64;
            float mi = mrun[ah][i], si = srun[ah][i];
#pragma unroll
            for (int bh = 0; bh < 2; ++bh)
#pragma unroll
            for (int j = 0; j < 4; ++j) {
                const int gcol = colBase + tx * 4 + j + bh * 64;
                if (gcol == grow) continue;   // mask self-similarity
                const float v = acc[ah][i][bh][j] * INV_T;
                if (v <= mi) {
                    si += __expf(v - mi);
                } else {
                    si = si * __expf(mi - v) + 1.0f;  // exp(-inf)=0 on first hit
                    mi = v;
                }
            }
            mrun[ah][i] = mi; srun[ah][i] = si;
        }
    }

    // Merge the 16 tx-partials per row, emit one (m, s) per (row, slice).
    __syncthreads();
#pragma unroll
    for (int ah = 0; ah < 2; ++ah)
#pragma unroll
    for (int i = 0; i < 4; ++i) {
        const int lr = ty * 4 + i + ah * 64;
        sm[lr][tx] = mrun[ah][i];
        ss[lr][tx] = srun[ah][i];
    }
    __syncthreads();
    if (tid < TM) {
        float M = -INFINITY;
#pragma unroll
        for (int x = 0; x < 16; ++x) M = fmaxf(M, sm[tid][x]);
        float S = 0.0f;
#pragma unroll
        for (int x = 0; x < 16; ++x) S += ss[tid][x] * __expf(sm[tid][x] - M);
        part_m[(size_t)(rowBase + tid) * NSLICE + slice] = M;
        part_s[(size_t)(rowBase + tid) * NSLICE + slice] = S;
    }
}

// Kernel P: pos[i] = dot(z[i], z[i+1]) / T, one wave per row.
__global__ __launch_bounds__(256) void pos_kernel(
    const float* __restrict__ z, float* __restrict__ pos)
{
    const int wave = (blockIdx.x * blockDim.x + threadIdx.x) >> 6;
    const int lane = threadIdx.x & 63;
    if (wave >= NROWS - 1) return;
    const float4 av = *(const float4*)(z + (size_t)wave * DIM + lane * 4);
    const float4 bv = *(const float4*)(z + (size_t)(wave + 1) * DIM + lane * 4);
    float sum = av.x * bv.x + av.y * bv.y + av.z * bv.z + av.w * bv.w;
#pragma unroll
    for (int off = 32; off > 0; off >>= 1) sum += __shfl_down(sum, off);
    if (lane == 0) pos[wave] = sum * INV_T;
}

// Kernel F: combine slice partials -> lse per row; loss = mean over valid
// pairs of (lse[i] - pos[i]), valid iff i % L != L-1. Single block.
__global__ __launch_bounds__(256) void final_kernel(
    const float* __restrict__ part_m, const float* __restrict__ part_s,
    const float* __restrict__ pos, float* __restrict__ out)
{
    __shared__ float red[256];
    const int tid = threadIdx.x;
    float local = 0.0f;
    for (int i = tid; i < NROWS - 1; i += 256) {
        if ((i & 255) == 255) continue;   // t == L-1: no positive pair
        const float* pm = part_m + (size_t)i * NSLICE;
        const float* ps = part_s + (size_t)i * NSLICE;
        float M = -INFINITY;
#pragma unroll
        for (int x = 0; x < NSLICE; ++x) M = fmaxf(M, pm[x]);
        float S = 0.0f;
#pragma unroll
        for (int x = 0; x < NSLICE; ++x) S += ps[x] * __expf(pm[x] - M);
        const float lse = M + logf(S);
        local += lse - pos[i];
    }
    red[tid] = local;
    __syncthreads();
    for (int st = 128; st > 0; st >>= 1) {
        if (tid < st) red[tid] += red[tid + st];
        __syncthreads();
    }
    if (tid == 0) out[0] = red[0] / 4080.0f;   // B*(L-1) valid pairs
}

extern "C" void kernel_launch(void* const* d_in, const int* in_sizes, int n_in,
                              void* d_out, int out_size, void* d_ws, size_t ws_size,
                              hipStream_t stream) {
    const float* z   = (const float*)d_in[0];   // [4096, 256]
    // d_in[1] = va_values: dead code in the reference, unused.
    const float* mem = (const float*)d_in[2];   // [16384, 256]

    // Workspace layout (fp32): part_m[4096*16] | part_s[4096*16] | pos[4096]
    float* part_m = (float*)d_ws;
    float* part_s = part_m + (size_t)NROWS * NSLICE;
    float* pos    = part_s + (size_t)NROWS * NSLICE;

    dim3 gridA(NROWS / TM, NSLICE);   // 32 x 16 = 512 blocks
    lse_partial_kernel<<<gridA, dim3(256), 0, stream>>>(z, mem, part_m, part_s);
    pos_kernel<<<dim3((NROWS + 3) / 4), dim3(256), 0, stream>>>(z, pos);
    final_kernel<<<dim3(1), dim3(256), 0, stream>>>(part_m, part_s, pos, (float*)d_out);
}

// Round 2
// 174.993 us; speedup vs baseline: 3.6296x; 3.6296x over previous
//
#include <hip/hip_runtime.h>
#include <hip/hip_bf16.h>
#include <math.h>

// Problem constants (B=16, L=256, D=256, K=16384)
#define NROWS 4096               // B*L anchors / z rows
#define KMEM  16384
#define NCAND 20480              // NROWS + KMEM candidates
#define DIM   256                // feature dim
#define TM    128                // anchor rows per block
#define TN    128                // candidate cols per tile
#define BK    64                 // k-depth per LDS stage (bf16)
#define NSLICE 16                // candidate column slices (grid.y)
#define COLS_PER_SLICE (NCAND / NSLICE)       // 1280
#define TILES_PER_SLICE (COLS_PER_SLICE / TN) // 10
#define INV_T  (1.0f / 0.07f)
#define SCALE2 (1.4426950408889634f / 0.07f)  // log2(e)/T, folded into A
#define LN2    0.6931471805599453f

typedef short  short8 __attribute__((ext_vector_type(8)));  // 8 bf16 (4 VGPRs)
typedef float  f32x4  __attribute__((ext_vector_type(4)));  // MFMA C/D
typedef unsigned short ushort_t;

// RNE float->bf16 (inputs are finite normals; no NaN path needed)
__device__ inline ushort_t f2bf(float x) {
    union { float f; unsigned u; } a; a.f = x;
    unsigned r = a.u + 0x7fff + ((a.u >> 16) & 1);
    return (ushort_t)(r >> 16);
}

// async global->LDS, 16B per lane, dest = wave-uniform base + lane*16
__device__ inline void load_lds16(const void* g, void* l) {
    __builtin_amdgcn_global_load_lds(
        (const __attribute__((address_space(1))) unsigned int*)g,
        (__attribute__((address_space(3))) unsigned int*)l, 16, 0, 0);
}

// Kernel 0: cast fp32 -> bf16. cand = [z ; mem] rows (unscaled, B-side);
// aS = z rows pre-scaled by SCALE2 (A-side, so MFMA output is base-2 logits).
__global__ __launch_bounds__(256) void cast_kernel(
    const float* __restrict__ z, const float* __restrict__ mem,
    ushort_t* __restrict__ aS, ushort_t* __restrict__ cand)
{
    const int idx = blockIdx.x * 256 + threadIdx.x;  // float4 index
    const int ZQ = NROWS * DIM / 4;                  // 262144
    if (idx < ZQ) {
        const float4 v = ((const float4*)z)[idx];
        ushort4 u; u.x = f2bf(v.x); u.y = f2bf(v.y); u.z = f2bf(v.z); u.w = f2bf(v.w);
        ((ushort4*)cand)[idx] = u;
        ushort4 a; a.x = f2bf(v.x * SCALE2); a.y = f2bf(v.y * SCALE2);
        a.z = f2bf(v.z * SCALE2); a.w = f2bf(v.w * SCALE2);
        ((ushort4*)aS)[idx] = a;
    } else {
        const int j = idx - ZQ;                      // < KMEM*DIM/4
        const float4 v = ((const float4*)mem)[j];
        ushort4 u; u.x = f2bf(v.x); u.y = f2bf(v.y); u.z = f2bf(v.z); u.w = f2bf(v.w);
        ((ushort4*)(cand + (size_t)NROWS * DIM))[j] = u;
    }
}

// Kernel A: MFMA flash-LSE. Block = 4 waves (2x2), 128 rows x 1280 cols/slice.
// Per 128x128 col-tile: K-loop stages A/B (128xBK bf16) into LDS via
// global_load_lds w=16 with XOR chunk swizzle (2-way bank alias = free),
// 16x16x32 bf16 MFMA into 4x4 f32x4 acc, then per-lane online (m,s) update
// in base-2 (A pre-scaled by log2(e)/T). Cross-lane merge once at the end.
__global__ __launch_bounds__(256) void mfma_lse_kernel(
    const ushort_t* __restrict__ aS, const ushort_t* __restrict__ cand,
    float* __restrict__ part_m, float* __restrict__ part_s)
{
    __shared__ __align__(16) char smem_raw[32768];
    ushort_t* ldsA = (ushort_t*)smem_raw;        // [128][BK] bf16, chunk-swizzled
    ushort_t* ldsB = ldsA + TM * BK;             // [128][BK]

    const int tid  = threadIdx.x;
    const int lane = tid & 63;
    const int w    = tid >> 6;        // wave 0..3
    const int wr   = w >> 1;          // wave row half (0/1)
    const int wc   = w & 1;           // wave col half
    const int quad = lane >> 4;
    const int ln   = lane & 15;
    const int rowBase = blockIdx.x * TM;
    const int slice   = blockIdx.y;

    // Per-lane online-softmax state for the 16 rows this lane owns in C-layout
    float m2[16], s[16];
#pragma unroll
    for (int i = 0; i < 16; ++i) { m2[i] = -INFINITY; s[i] = 0.0f; }

    for (int t = 0; t < TILES_PER_SLICE; ++t) {
        const int colBase = slice * COLS_PER_SLICE + t * TN;
        f32x4 acc[4][4];
#pragma unroll
        for (int ti = 0; ti < 4; ++ti)
#pragma unroll
            for (int tj = 0; tj < 4; ++tj) acc[ti][tj] = (f32x4)0.0f;

        for (int kk = 0; kk < DIM; kk += BK) {
            __syncthreads();   // previous stage's LDS reads complete
            // Stage: wave w covers tile rows [w*32, w*32+32). Each instr:
            // 64 lanes x 16B = 8 rows. Lane l -> row +l/8, LDS chunk l%8,
            // global chunk c = (l%8) ^ (row&7)  (XOR swizzle, coalescing kept:
            // 8-lane groups cover a full 128B row segment as a permutation).
#pragma unroll
            for (int u = 0; u < 4; ++u) {
                const int r  = w * 32 + u * 8 + (lane >> 3);
                const int c  = (lane & 7) ^ (r & 7);
                load_lds16(aS   + (size_t)(rowBase + r) * DIM + kk + c * 8,
                           ldsA + (w * 32 + u * 8) * BK);
                load_lds16(cand + (size_t)(colBase + r) * DIM + kk + c * 8,
                           ldsB + (w * 32 + u * 8) * BK);
            }
            __syncthreads();   // drains vmcnt (global_load_lds) before reads

            // 2 k-steps of 32 depth each; A-frag: lane holds A[m=ln][k=quad*8+j]
#pragma unroll
            for (int ks = 0; ks < 2; ++ks) {
                short8 af[4], bfr[4];
#pragma unroll
                for (int ti = 0; ti < 4; ++ti) {
                    const int row = wr * 64 + ti * 16 + ln;
                    const int p = row * 8 + ((ks * 4 + quad) ^ (row & 7));
                    af[ti] = *(const short8*)(ldsA + p * 8);
                }
#pragma unroll
                for (int tj = 0; tj < 4; ++tj) {
                    const int col = wc * 64 + tj * 16 + ln;
                    const int p = col * 8 + ((ks * 4 + quad) ^ (col & 7));
                    bfr[tj] = *(const short8*)(ldsB + p * 8);
                }
#pragma unroll
                for (int ti = 0; ti < 4; ++ti)
#pragma unroll
                    for (int tj = 0; tj < 4; ++tj)
                        acc[ti][tj] = __builtin_amdgcn_mfma_f32_16x16x32_bf16(
                            af[ti], bfr[tj], acc[ti][tj], 0, 0, 0);
            }
        }

        // Epilogue: base-2 online update, per-lane only (no shuffles).
        // C/D layout: col = ln (+16*tj +64*wc), row = quad*4+reg (+16*ti +64*wr)
        const bool hasDiag = (colBase < rowBase + TM) && (rowBase < colBase + TN);
#pragma unroll
        for (int ti = 0; ti < 4; ++ti) {
#pragma unroll
            for (int r = 0; r < 4; ++r) {
                const int idx = ti * 4 + r;
                float v0 = acc[ti][0][r], v1 = acc[ti][1][r];
                float v2 = acc[ti][2][r], v3 = acc[ti][3][r];
                if (hasDiag) {
                    const int grow = rowBase + wr * 64 + ti * 16 + quad * 4 + r;
                    const int gc0  = colBase + wc * 64 + ln;
                    if (gc0      == grow) v0 = -3.0e38f;   // mask self-sim
                    if (gc0 + 16 == grow) v1 = -3.0e38f;
                    if (gc0 + 32 == grow) v2 = -3.0e38f;
                    if (gc0 + 48 == grow) v3 = -3.0e38f;
                }
                const float tmax = fmaxf(fmaxf(v0, v1), fmaxf(v2, v3));
                const float mo = m2[idx];
                const float mn = fmaxf(mo, tmax);          // finite: tmax finite
                const float sc = __builtin_amdgcn_exp2f(mo - mn);  // exp2(-inf)=0
                s[idx] = s[idx] * sc
                       + __builtin_amdgcn_exp2f(v0 - mn) + __builtin_amdgcn_exp2f(v1 - mn)
                       + __builtin_amdgcn_exp2f(v2 - mn) + __builtin_amdgcn_exp2f(v3 - mn);
                m2[idx] = mn;
            }
        }
    }

    // Cross-lane merge: 32 partials per row (16 ln x 2 wc), via LDS overlay.
    __syncthreads();                       // all tile reads done; reuse smem
    float* smf = (float*)smem_raw;         // [128][32] m partials
    float* ssf = smf + TM * 32;            // [128][32] s partials
    const int p = wc * 16 + ln;
#pragma unroll
    for (int ti = 0; ti < 4; ++ti)
#pragma unroll
        for (int r = 0; r < 4; ++r) {
            const int rl = wr * 64 + ti * 16 + quad * 4 + r;
            smf[rl * 32 + p] = m2[ti * 4 + r];
            ssf[rl * 32 + p] = s[ti * 4 + r];
        }
    __syncthreads();
    if (tid < TM) {
        float M = -INFINITY;
#pragma unroll
        for (int x = 0; x < 32; ++x) M = fmaxf(M, smf[tid * 32 + x]);
        float S = 0.0f;
#pragma unroll
        for (int x = 0; x < 32; ++x)
            S += ssf[tid * 32 + x] * __builtin_amdgcn_exp2f(smf[tid * 32 + x] - M);
        part_m[(size_t)(rowBase + tid) * NSLICE + slice] = M;
        part_s[(size_t)(rowBase + tid) * NSLICE + slice] = S;
    }
}

// Kernel P: pos[i] = dot(z[i], z[i+1]) / T in exact fp32, one wave per row.
__global__ __launch_bounds__(256) void pos_kernel(
    const float* __restrict__ z, float* __restrict__ pos)
{
    const int wave = (blockIdx.x * blockDim.x + threadIdx.x) >> 6;
    const int lane = threadIdx.x & 63;
    if (wave >= NROWS - 1) return;
    const float4 av = *(const float4*)(z + (size_t)wave * DIM + lane * 4);
    const float4 bv = *(const float4*)(z + (size_t)(wave + 1) * DIM + lane * 4);
    float sum = av.x * bv.x + av.y * bv.y + av.z * bv.z + av.w * bv.w;
#pragma unroll
    for (int off = 32; off > 0; off >>= 1) sum += __shfl_down(sum, off);
    if (lane == 0) pos[wave] = sum * INV_T;
}

// Kernel F: combine slice partials (base-2) -> lse (natural log) -> loss.
__global__ __launch_bounds__(256) void final_kernel(
    const float* __restrict__ part_m, const float* __restrict__ part_s,
    const float* __restrict__ pos, float* __restrict__ out)
{
    __shared__ float red[256];
    const int tid = threadIdx.x;
    float local = 0.0f;
    for (int i = tid; i < NROWS - 1; i += 256) {
        if ((i & 255) == 255) continue;   // t == L-1: no positive pair
        const float* pm = part_m + (size_t)i * NSLICE;
        const float* ps = part_s + (size_t)i * NSLICE;
        float M = -INFINITY;
#pragma unroll
        for (int x = 0; x < NSLICE; ++x) M = fmaxf(M, pm[x]);
        float S = 0.0f;
#pragma unroll
        for (int x = 0; x < NSLICE; ++x)
            S += ps[x] * __builtin_amdgcn_exp2f(pm[x] - M);
        const float lse = LN2 * (M + __builtin_amdgcn_logf(S));  // v_log = log2
        local += lse - pos[i];
    }
    red[tid] = local;
    __syncthreads();
    for (int st = 128; st > 0; st >>= 1) {
        if (tid < st) red[tid] += red[tid + st];
        __syncthreads();
    }
    if (tid == 0) out[0] = red[0] / 4080.0f;   // B*(L-1) valid pairs
}

extern "C" void kernel_launch(void* const* d_in, const int* in_sizes, int n_in,
                              void* d_out, int out_size, void* d_ws, size_t ws_size,
                              hipStream_t stream) {
    const float* z   = (const float*)d_in[0];   // [4096, 256]
    // d_in[1] = va_values: dead code in the reference, unused.
    const float* mem = (const float*)d_in[2];   // [16384, 256]

    // ws layout (bytes): cand bf16 [20480*256] | aS bf16 [4096*256]
    //                  | part_m f32 [4096*16] | part_s f32 [4096*16] | pos f32 [4096]
    ushort_t* cand = (ushort_t*)d_ws;
    ushort_t* aS   = cand + (size_t)NCAND * DIM;
    float* part_m  = (float*)(aS + (size_t)NROWS * DIM);
    float* part_s  = part_m + (size_t)NROWS * NSLICE;
    float* pos     = part_s + (size_t)NROWS * NSLICE;

    const int castBlocks = (NROWS + KMEM) * DIM / 4 / 256;   // 5120
    cast_kernel<<<dim3(castBlocks), dim3(256), 0, stream>>>(z, mem, aS, cand);
    mfma_lse_kernel<<<dim3(NROWS / TM, NSLICE), dim3(256), 0, stream>>>(
        aS, cand, part_m, part_s);
    pos_kernel<<<dim3((NROWS + 3) / 4), dim3(256), 0, stream>>>(z, pos);
    final_kernel<<<dim3(1), dim3(256), 0, stream>>>(part_m, part_s, pos, (float*)d_out);
}